// Round 3
// baseline (254.108 us; speedup 1.0000x reference)
//
#include <hip/hip_runtime.h>
#include <stdint.h>

#define BATCH 64
#define HH 512
#define NR 256
#define BANDH 8
#define NBANDS (256 / BANDH)   // 32 bands over dy' in [0,256)

// LDS aperture: low 32 bits of a generic pointer to __shared__ = LDS offset.
__device__ __forceinline__ uint32_t lds_off(const void* p) {
    return (uint32_t)(uintptr_t)p;
}

// Native fire-and-forget LDS fp32 atomics into 4 comp-major tables of 257
// floats (strides 1028 B). Ordering vs the merge phase is enforced by the
// explicit waitcnt asm + __syncthreads.
__device__ __forceinline__ void lds_add4(uint32_t addr, float v0, float v1,
                                         float v2, float v3) {
    asm volatile(
        "ds_add_f32 %0, %1\n\t"
        "ds_add_f32 %0, %2 offset:1028\n\t"
        "ds_add_f32 %0, %3 offset:2056\n\t"
        "ds_add_f32 %0, %4 offset:3084"
        :: "v"(addr), "v"(v0), "v"(v1), "v"(v2), "v"(v3));
}

// Forced-MLP scalar load: SGPR base (block-uniform) + 32-bit lane byte offset.
// asm volatile => program order preserved; 16 of these stay in flight until
// the single vmcnt(0) below. hipcc's own scheduler (VGPR-minimizing) was
// serializing these into latency-bound groups — VGPR_Count=40/48 in rounds
// 0-2 proves the source-level "loads up front" never survived regalloc.
__device__ __forceinline__ float gld(uint64_t base, uint32_t off) {
    float r;
    asm volatile("global_load_dword %0, %1, %2"
                 : "=v"(r) : "v"(off), "s"(base));
    return r;
}

// 4-fold mirror + column-run-length scatter; identical to the round-2 kernel
// except the 16 row loads are inline-asm with one wave-level vmcnt(0) drain.
__global__ __launch_bounds__(256) void frc_fold(
    const float* __restrict__ f1r, const float* __restrict__ f1i,
    const float* __restrict__ f2r, const float* __restrict__ f2i,
    float* __restrict__ gpart /* [NBANDS][BATCH][4][NR] */)
{
    __shared__ float s_acc[4 * 257];   // [comp][bin], bin 256 = overflow
    for (int i = threadIdx.x; i < 4 * 257; i += 256) s_acc[i] = 0.f;
    __syncthreads();

    const int b    = blockIdx.y;
    const int band = blockIdx.x;
    const int w    = threadIdx.x >> 6;
    const int lane = threadIdx.x & 63;
    const int dx   = w * 64 + lane;          // 0..255
    const int dx2  = dx * dx;
    const int wmin2 = (w * 64) * (w * 64);   // min dx^2 in this wave
    const float mx = (dx == 0) ? 0.f : 1.f;  // dx=0 is its own x-mirror

    const int dy0 = band * BANDH;
    const size_t ib = (size_t)b * HH * HH;

    // Block-uniform 64-bit bases (land in SGPR pairs for the asm loads).
    const uint64_t b1r = (uint64_t)(uintptr_t)(f1r + ib);
    const uint64_t b1i = (uint64_t)(uintptr_t)(f1i + ib);
    const uint64_t b2r = (uint64_t)(uintptr_t)(f2r + ib);
    const uint64_t b2i = (uint64_t)(uintptr_t)(f2i + ib);

    const uint32_t oxp = (uint32_t)(256 + dx) * 4u;   // byte offset, col 256..511
    const uint32_t oxm = (uint32_t)(256 - dx) * 4u;   // byte offset, col 1..256

    const uint32_t sbase = lds_off(s_acc);

    float acr = 0.f, aci = 0.f, ap1 = 0.f, ap2 = 0.f;
    int cur = -1;

    for (int dy = dy0; dy < dy0 + BANDH; ++dy) {
        if (wmin2 + dy * dy >= 65536) break;  // whole wave in overflow bins

        const int r2 = dx2 + dy * dy;         // < 2^18, exact in fp32
        int bin = (int)sqrtf((float)r2);
        bin -= (bin * bin > r2);
        bin += ((bin + 1) * (bin + 1) <= r2);
        if (bin > 256) bin = 256;

        const float my = (dy == 0) ? 0.f : 1.f;  // dy=0 is its own y-mirror

        const uint32_t rpb = (uint32_t)(256 + dy) * (HH * 4u);
        const uint32_t rmb = (uint32_t)(256 - dy) * (HH * 4u);
        const uint32_t opp = rpb + oxp;
        const uint32_t opm = rpb + oxm;
        const uint32_t omp = rmb + oxp;
        const uint32_t omm = rmb + oxm;

        // ---- 16 loads issued back-to-back, all in flight until vmcnt(0) ----
        const float A1 = gld(b1r, opp), B1 = gld(b1i, opp);
        const float A2 = gld(b2r, opp), B2 = gld(b2i, opp);
        const float C1 = gld(b1r, opm), D1 = gld(b1i, opm);
        const float C2 = gld(b2r, opm), D2 = gld(b2i, opm);
        const float E1 = gld(b1r, omp), G1 = gld(b1i, omp);
        const float E2 = gld(b2r, omp), G2 = gld(b2i, omp);
        const float P1 = gld(b1r, omm), Q1 = gld(b1i, omm);
        const float P2 = gld(b2r, omm), Q2 = gld(b2i, omm);

        asm volatile("s_waitcnt vmcnt(0)" ::: "memory");
        __builtin_amdgcn_sched_barrier(0);   // rule 18: no consumer hoisting

        // folded products over up to 4 mirror pixels
        float scr = A1 * A2 + B1 * B2;
        float sci = B1 * A2 - A1 * B2;
        float sp1 = A1 * A1 + B1 * B1;
        float sp2 = A2 * A2 + B2 * B2;

        scr += mx * (C1 * C2 + D1 * D2);
        sci += mx * (D1 * C2 - C1 * D2);
        sp1 += mx * (C1 * C1 + D1 * D1);
        sp2 += mx * (C2 * C2 + D2 * D2);

        scr += my * (E1 * E2 + G1 * G2);
        sci += my * (G1 * E2 - E1 * G2);
        sp1 += my * (E1 * E1 + G1 * G1);
        sp2 += my * (E2 * E2 + G2 * G2);

        const float mxy = mx * my;
        scr += mxy * (P1 * P2 + Q1 * Q2);
        sci += mxy * (Q1 * P2 - P1 * Q2);
        sp1 += mxy * (P1 * P1 + Q1 * Q1);
        sp2 += mxy * (P2 * P2 + Q2 * Q2);

        if (bin != cur) {
            if (cur >= 0)
                lds_add4(sbase + 4u * (uint32_t)cur, acr, aci, ap1, ap2);
            acr = 0.f; aci = 0.f; ap1 = 0.f; ap2 = 0.f;
            cur = bin;
        }
        acr += scr; aci += sci; ap1 += sp1; ap2 += sp2;
    }
    if (cur >= 0)
        lds_add4(sbase + 4u * (uint32_t)cur, acr, aci, ap1, ap2);

    // Drain the asm DS ops the compiler can't see, then merge.
    asm volatile("s_waitcnt lgkmcnt(0)" ::: "memory");
    __syncthreads();

    {
        // Plain coalesced stores into this block's private slice (round-2
        // atomic-free merge, proven neutral-to-positive).
        const int r = threadIdx.x;  // 256 threads -> bins 0..255 (drop 256)
        float* g = gpart + ((size_t)(band * BATCH + b) * 4) * NR + r;
        g[0 * NR] = s_acc[0 * 257 + r];
        g[1 * NR] = s_acc[1 * 257 + r];
        g[2 * NR] = s_acc[2 * 257 + r];
        g[3 * NR] = s_acc[3 * 257 + r];
    }
}

__global__ __launch_bounds__(NR) void frc_finalize(
    const float* __restrict__ gpart, float* __restrict__ out)
{
    const int b = blockIdx.x;
    const int r = threadIdx.x;
    float cr = 0.f, ci = 0.f, p1 = 0.f, p2 = 0.f;
    for (int band = 0; band < NBANDS; ++band) {
        const float* g = gpart + ((size_t)(band * BATCH + b) * 4) * NR + r;
        cr += g[0 * NR];
        ci += g[1 * NR];
        p1 += g[2 * NR];
        p2 += g[3 * NR];
    }
    const float num = sqrtf(cr * cr + ci * ci);
    const float den = sqrtf(p1 * p2);
    out[(size_t)b * NR + r] = (den == 0.f) ? 0.f : num / den;
}

extern "C" void kernel_launch(void* const* d_in, const int* in_sizes, int n_in,
                              void* d_out, int out_size, void* d_ws, size_t ws_size,
                              hipStream_t stream) {
    const float* f1r = (const float*)d_in[0];
    const float* f1i = (const float*)d_in[1];
    const float* f2r = (const float*)d_in[2];
    const float* f2i = (const float*)d_in[3];
    float* out   = (float*)d_out;
    float* gpart = (float*)d_ws;   // NBANDS*BATCH*4*NR floats = 8 MiB

    (void)in_sizes; (void)n_in; (void)out_size; (void)ws_size;

    dim3 grid(NBANDS, BATCH);   // 32 x 64 = 2048 blocks, 8/CU
    frc_fold<<<grid, 256, 0, stream>>>(f1r, f1i, f2r, f2i, gpart);
    frc_finalize<<<dim3(BATCH), dim3(NR), 0, stream>>>(gpart, out);
}